// Round 15
// baseline (121.409 us; speedup 1.0000x reference)
//
#include <hip/hip_runtime.h>
#include <cstdint>
#include <cstddef>

// GraphAttentionLayer: N=8192, IN=512, OUT=256
//  k0: w1=W@W2[:256], w2=W@W2[256:], WTbf = bf16(W^T) fragment image, maxkey=0
//  k2f: WhTf = bf16(X@W)^T fragment image + Wh1/Wh2 (exact fp32) + max
//  k3: fused (r14 frame: 1024 thr, 256 blocks = 1/CU, stagger, lgkm-only
//      barrier) with KSPLIT=2 (PVp partial traffic halved) at constant
//      occupancy via IROWS=64 + BKJ=128 (NSTEP stays 32). A-image 16 units
//      (unit = rg*4+ks). B in-iter regs. T5 setprio around MFMA cluster.
//  k4: reduce 2 partials, divide by Z, relu
#define NR 8192
#define FOUT 256
#define KIN 512
#define KSPLIT 2
#define JCHUNK (NR / KSPLIT)  // 4096
#define BKJ 128
#define NSTEP (JCHUNK / BKJ)  // 32
#define IROWS 64

typedef __attribute__((ext_vector_type(8))) short bf16x8;
typedef __attribute__((ext_vector_type(4))) float f32x4;

__device__ __forceinline__ unsigned f2bf(float x) {
  unsigned u = __float_as_uint(x);
  u += 0x7fffu + ((u >> 16) & 1u);
  return u >> 16;
}
__device__ __forceinline__ float bf2f(unsigned h) {
  return __uint_as_float(h << 16);
}
// monotone float<->uint key for atomicMax (0 == -inf sentinel)
__device__ __forceinline__ unsigned fkey(float x) {
  unsigned u = __float_as_uint(x);
  return (u & 0x80000000u) ? ~u : (u | 0x80000000u);
}
__device__ __forceinline__ float fkey_dec(unsigned k) {
  return __uint_as_float((k & 0x80000000u) ? (k ^ 0x80000000u) : ~k);
}

#define GLDS(g, l)                                                            \
  __builtin_amdgcn_global_load_lds(                                           \
      (const __attribute__((address_space(1))) unsigned int*)(g),             \
      (__attribute__((address_space(3))) unsigned int*)(l), 16, 0, 0)

// ---------------- k0: w1, w2, WTbf (B-fragment image), maxkey init ---------
__global__ __launch_bounds__(256) void k0_prep(const float* __restrict__ W,
                                               const float* __restrict__ W2,
                                               float* __restrict__ w1,
                                               float* __restrict__ w2,
                                               char* __restrict__ WTbf,
                                               unsigned* __restrict__ maxkey) {
  if (blockIdx.x == 0 && threadIdx.x == 0) *maxkey = 0u;
  int wv = threadIdx.x >> 6, lane = threadIdx.x & 63;
  int k = blockIdx.x * 4 + wv;  // 0..511
  int f4 = lane * 4;
  float4 wr = *(const float4*)(W + (size_t)k * FOUT + f4);
  float4 a = *(const float4*)(W2 + f4);
  float4 b = *(const float4*)(W2 + FOUT + f4);
  float d1 = wr.x * a.x + wr.y * a.y + wr.z * a.z + wr.w * a.w;
  float d2 = wr.x * b.x + wr.y * b.y + wr.z * b.z + wr.w * b.w;
#pragma unroll
  for (int off = 32; off; off >>= 1) {
    d1 += __shfl_xor(d1, off);
    d2 += __shfl_xor(d2, off);
  }
  if (lane == 0) {
    w1[k] = d1;
    w2[k] = d2;
  }
  int kt = k >> 5, kl = k & 31;
  float wv4[4] = {wr.x, wr.y, wr.z, wr.w};
#pragma unroll
  for (int ff = 0; ff < 4; ++ff) {
    int f = f4 + ff;
    size_t addr = (size_t)kt * 16384 + (f >> 4) * 1024 +
                  (((f & 15) | (((kl >> 3) & 3) << 4)) * 16) + (kl & 7) * 2;
    *(unsigned short*)(WTbf + addr) = (unsigned short)f2bf(wv4[ff]);
  }
}

// ---------------- k2f: WhTf fragment image + Wh1/Wh2 + maxkey --------------
__global__ __launch_bounds__(256) void k2_fused(
    const float* __restrict__ X, const char* __restrict__ WTbf,
    const float* __restrict__ w1, const float* __restrict__ w2,
    char* __restrict__ WhTf, float* __restrict__ Wh1, float* __restrict__ Wh2,
    unsigned* __restrict__ maxkey) {
  // [dbuf: 2 x (A 2KB + B 16KB)][w-slices 4KB]
  __shared__ char smem[2 * 18432 + 4096];
  char* buf0 = smem;
  char* buf1 = smem + 18432;
  char* wlds = smem + 2 * 18432;  // w1 floats [0,2048), w2 floats [2048,4096)
  int t = threadIdx.x, wv = t >> 6, lane = t & 63;
  int jb = blockIdx.x * 32;
  int jr = t >> 3, koff = (t & 7) * 4;
  int cA = (jr & 15) | (((koff >> 3) & 3) << 4);
  int swA = cA ^ (((cA >> 4) & 3) << 2);
  int aoff = (jr >> 4) * 1024 + swA * 16 + ((koff & 4) << 1);
  int slotR = lane ^ (((lane >> 4) & 3) << 2);
  const float* xrow = X + (size_t)(jb + jr) * KIN + koff;

  // Stage w1/w2 into LDS (reads via lgkm, so they don't pollute vmcnt).
  {
    float2 a_ = *(const float2*)(w1 + t * 2);
    float2 b_ = *(const float2*)(w2 + t * 2);
    *(float2*)(wlds + t * 8) = a_;
    *(float2*)(wlds + 2048 + t * 8) = b_;
  }
  __syncthreads();

  float4 st0, st1, st2, st3;
  float d1 = 0.f, d2 = 0.f;
  f32x4 acc[2][4];
#pragma unroll
  for (int a = 0; a < 2; ++a)
#pragma unroll
    for (int b = 0; b < 4; ++b) acc[a][b] = (f32x4){0.f, 0.f, 0.f, 0.f};

#define K2_GLB(KT, BUFW)                                                      \
  do {                                                                        \
    const char* gs_ = WTbf + ((size_t)(KT) << 14) + (wv << 12) + lane * 16;   \
    char* ld_ = (BUFW) + 2048 + (wv << 12);                                   \
    GLDS(gs_, ld_);                                                           \
    GLDS(gs_ + 1024, ld_ + 1024);                                             \
    GLDS(gs_ + 2048, ld_ + 2048);                                             \
    GLDS(gs_ + 3072, ld_ + 3072);                                             \
  } while (0)

#define K2_LDX(KT, ST) (ST) = *(const float4*)(xrow + (KT) * 32)

#define K2_AGEN(ST, BUFW, SNUM)                                               \
  do {                                                                        \
    uint2 a_;                                                                 \
    a_.x = f2bf((ST).x) | (f2bf((ST).y) << 16);                               \
    a_.y = f2bf((ST).z) | (f2bf((ST).w) << 16);                               \
    *(uint2*)((BUFW) + aoff) = a_;                                            \
    float4 wa_ = *(const float4*)(wlds + ((SNUM)*32 + koff) * 4);             \
    float4 wb_ = *(const float4*)(wlds + 2048 + ((SNUM)*32 + koff) * 4);      \
    d1 += (ST).x * wa_.x + (ST).y * wa_.y + (ST).z * wa_.z + (ST).w * wa_.w;  \
    d2 += (ST).x * wb_.x + (ST).y * wb_.y + (ST).z * wb_.z + (ST).w * wb_.w;  \
  } while (0)

#define K2_ITER(S, BUFR, BUFW, STC, STF)                                      \
  do {                                                                        \
    int s_ = (S);                                                             \
    if (s_ + 1 < 16) K2_GLB(s_ + 1, BUFW);                                    \
    K2_LDX((s_ + 3 < 16) ? s_ + 3 : 15, STF);                                 \
    if (s_ + 1 < 16) K2_AGEN(STC, BUFW, s_ + 1);                              \
    bf16x8 a0 = *(const bf16x8*)((BUFR) + slotR * 16);                        \
    bf16x8 a1 = *(const bf16x8*)((BUFR) + 1024 + slotR * 16);                 \
    bf16x8 b0 = *(const bf16x8*)((BUFR) + 2048 + (wv * 4 + 0) * 1024 + lane * 16); \
    bf16x8 b1 = *(const bf16x8*)((BUFR) + 2048 + (wv * 4 + 1) * 1024 + lane * 16); \
    bf16x8 b2 = *(const bf16x8*)((BUFR) + 2048 + (wv * 4 + 2) * 1024 + lane * 16); \
    bf16x8 b3 = *(const bf16x8*)((BUFR) + 2048 + (wv * 4 + 3) * 1024 + lane * 16); \
    acc[0][0] = __builtin_amdgcn_mfma_f32_16x16x32_bf16(a0, b0, acc[0][0], 0, 0, 0); \
    acc[0][1] = __builtin_amdgcn_mfma_f32_16x16x32_bf16(a0, b1, acc[0][1], 0, 0, 0); \
    acc[0][2] = __builtin_amdgcn_mfma_f32_16x16x32_bf16(a0, b2, acc[0][2], 0, 0, 0); \
    acc[0][3] = __builtin_amdgcn_mfma_f32_16x16x32_bf16(a0, b3, acc[0][3], 0, 0, 0); \
    acc[1][0] = __builtin_amdgcn_mfma_f32_16x16x32_bf16(a1, b0, acc[1][0], 0, 0, 0); \
    acc[1][1] = __builtin_amdgcn_mfma_f32_16x16x32_bf16(a1, b1, acc[1][1], 0, 0, 0); \
    acc[1][2] = __builtin_amdgcn_mfma_f32_16x16x32_bf16(a1, b2, acc[1][2], 0, 0, 0); \
    acc[1][3] = __builtin_amdgcn_mfma_f32_16x16x32_bf16(a1, b3, acc[1][3], 0, 0, 0); \
    __builtin_amdgcn_sched_barrier(0);                                        \
    asm volatile("s_waitcnt vmcnt(1)");                                       \
    asm volatile("s_waitcnt lgkmcnt(0)");                                     \
    __builtin_amdgcn_s_barrier();                                             \
    __builtin_amdgcn_sched_barrier(0);                                        \
  } while (0)

  // Prologue
  K2_GLB(0, buf0);
  K2_LDX(0, st0);
  K2_LDX(1, st1);
  K2_LDX(2, st2);
  K2_AGEN(st0, buf0, 0);
  __builtin_amdgcn_sched_barrier(0);
  asm volatile("s_waitcnt vmcnt(2)");
  asm volatile("s_waitcnt lgkmcnt(0)");
  __builtin_amdgcn_s_barrier();
  __builtin_amdgcn_sched_barrier(0);

  for (int s4 = 0; s4 < 16; s4 += 4) {
    K2_ITER(s4 + 0, buf0, buf1, st1, st3);
    K2_ITER(s4 + 1, buf1, buf0, st2, st0);
    K2_ITER(s4 + 2, buf0, buf1, st3, st1);
    K2_ITER(s4 + 3, buf1, buf0, st0, st2);
  }
#undef K2_ITER
#undef K2_AGEN
#undef K2_LDX
#undef K2_GLB

  // Epilogue A: fragment image for this 32-j tile into buf0 B-area, copy out.
  int q = lane >> 4;
#pragma unroll
  for (int mi = 0; mi < 2; ++mi)
#pragma unroll
    for (int nn = 0; nn < 4; ++nn) {
      int u2 = wv * 4 + nn;
      int cell = (lane & 15) | ((((mi * 2) + (q >> 1)) & 3) << 4);
      uint2 v;
      v.x = f2bf(acc[mi][nn].x) | (f2bf(acc[mi][nn].y) << 16);
      v.y = f2bf(acc[mi][nn].z) | (f2bf(acc[mi][nn].w) << 16);
      *(uint2*)(buf0 + 2048 + u2 * 1024 + cell * 16 + ((q & 1) << 3)) = v;
    }
  __syncthreads();
  char* wb = WhTf + (size_t)blockIdx.x * 16384;
#pragma unroll
  for (int q2 = 0; q2 < 4; ++q2) {
    uint4 v = *(const uint4*)(buf0 + 2048 + q2 * 4096 + t * 16);
    *(uint4*)(wb + q2 * 4096 + t * 16) = v;
  }

  // Epilogue B: reduce Wh1/Wh2 over the 8 lanes sharing row jr, write, max.
  d1 += __shfl_xor(d1, 1);
  d1 += __shfl_xor(d1, 2);
  d1 += __shfl_xor(d1, 4);
  d2 += __shfl_xor(d2, 1);
  d2 += __shfl_xor(d2, 2);
  d2 += __shfl_xor(d2, 4);
  if ((t & 7) == 0) {
    Wh1[jb + jr] = d1;
    Wh2[jb + jr] = d2;
  }
  float mx = d2;
#pragma unroll
  for (int off = 32; off >= 8; off >>= 1) mx = fmaxf(mx, __shfl_xor(mx, off));
  __shared__ float red[4];
  if (lane == 0) red[wv] = mx;
  __syncthreads();
  if (t == 0) {
    float bm = fmaxf(fmaxf(red[0], red[1]), fmaxf(red[2], red[3]));
    atomicMax(maxkey, fkey(bm));
  }
}

// ---------------- k3: fused attention weights + PV matmul ----------------
__device__ __forceinline__ uint2 hv4(int4 aq, float4 wq, float wh1, float m,
                                     float enm, float& z) {
  float s0 = wh1 + wq.x, s1 = wh1 + wq.y, s2 = wh1 + wq.z, s3 = wh1 + wq.w;
  s0 = fmaxf(s0, 0.2f * s0);
  s1 = fmaxf(s1, 0.2f * s1);
  s2 = fmaxf(s2, 0.2f * s2);
  s3 = fmaxf(s3, 0.2f * s3);
  float w0 = aq.x > 0 ? __expf(s0 - m) : enm;
  float w1 = aq.y > 0 ? __expf(s1 - m) : enm;
  float w2 = aq.z > 0 ? __expf(s2 - m) : enm;
  float w3 = aq.w > 0 ? __expf(s3 - m) : enm;
  unsigned h0 = f2bf(w0), h1 = f2bf(w1), h2 = f2bf(w2), h3 = f2bf(w3);
  z += bf2f(h0) + bf2f(h1) + bf2f(h2) + bf2f(h3);
  uint2 r;
  r.x = h0 | (h1 << 16);
  r.y = h2 | (h3 << 16);
  return r;
}
__device__ __forceinline__ uint4 hv8(int4 a0, int4 a1, float4 w0, float4 w1,
                                     float wh1, float m, float enm, float& z) {
  uint2 r0 = hv4(a0, w0, wh1, m, enm, z);
  uint2 r1 = hv4(a1, w1, wh1, m, enm, z);
  return (uint4){r0.x, r0.y, r1.x, r1.y};
}

__global__ __launch_bounds__(1024, 4) void k3_attn(
    const int* __restrict__ adj, const char* __restrict__ WhTf,
    const float* __restrict__ Wh1, const float* __restrict__ Wh2,
    const unsigned* __restrict__ maxptr, float* __restrict__ PVp,
    float* __restrict__ Zp) {
  // [A dbuf 2 x 16KB][wh2 chunk 16KB] = 49152 B
  __shared__ char smem[49152];
  char* abuf0 = smem;
  char* abuf1 = smem + 16384;
  char* wlds = smem + 32768;
  int t = threadIdx.x, wv = t >> 6, lane = t & 63;
  int kc = blockIdx.x & 1;
  int ib = blockIdx.x >> 1;  // 0..127
  int ibase = ib * IROWS;
  int jbch = kc * JCHUNK;
  int r0 = t >> 4;           // row in tile 0..63 (A-gen role)
  int j8 = (t & 15) * 8;     // j offset 0..120
  int iglob = ibase + r0;
  float maxwh2 = fkey_dec(*maxptr);
  float wh1 = Wh1[iglob];
  float m = fmaxf(0.f, wh1 + maxwh2);
  float enm = __expf(-m);
  // A-image: 16 units x 1KB; unit = rg*4 + ks (rg = r0>>4, ks = j8>>5).
  int unitA = (r0 >> 4) * 4 + (j8 >> 5);
  int cA = (r0 & 15) | (((j8 & 31) >> 3) << 4);
  int swA = cA ^ (((cA >> 4) & 3) << 2);
  int aoff = unitA * 1024 + swA * 16;
  int slotR = lane ^ (((lane >> 4) & 3) << 2);
  const int* adjrow = adj + ((size_t)iglob << 13) + jbch + j8;
  // MFMA role: wave (g = wv>>1, h = wv&1): f-units {2g,2g+1}, rgs {2h,2h+1}.
  int g = wv >> 1, h = wv & 1;
  const char* bbase = WhTf + ((size_t)(kc * 128) << 14) + (size_t)(2 * g) * 1024 +
                      (size_t)lane * 16;
  const char* wl = wlds + j8 * 4;

  // Stage this chunk's Wh2 (4096 floats = 16KB) into LDS once.
  *(float4*)(wlds + t * 16) = *(const float4*)(Wh2 + jbch + t * 4);
  __syncthreads();

  int4 st0_a, st0_b, st1_a, st1_b;
  f32x4 acc[2][2];
#pragma unroll
  for (int a = 0; a < 2; ++a)
#pragma unroll
    for (int b = 0; b < 2; ++b) acc[a][b] = (f32x4){0.f, 0.f, 0.f, 0.f};
  float zacc = 0.f;

#define K3_LDA(S, ST)                                                         \
  do {                                                                        \
    int sc_ = (S) < NSTEP ? (S) : NSTEP - 1;                                  \
    ST##_a = *(const int4*)(adjrow + sc_ * BKJ);                              \
    ST##_b = *(const int4*)(adjrow + sc_ * BKJ + 4);                          \
  } while (0)

#define K3_HV(S, AW, STC)                                                     \
  do {                                                                        \
    float4 wq0_ = *(const float4*)(wl + ((S) + 1) * 512);                     \
    float4 wq1_ = *(const float4*)(wl + ((S) + 1) * 512 + 16);                \
    uint4 a_ = hv8(STC##_a, STC##_b, wq0_, wq1_, wh1, m, enm, zacc);          \
    *(uint4*)((AW) + aoff) = a_;                                              \
  } while (0)

  // B(s) in-iter: 8 fragments (ks 0..3 x un 0..1) from the image.
#define K3_MFMA(S, AR)                                                        \
  do {                                                                        \
    const char* bp_ = bbase + ((size_t)(4 * (S)) << 14);                      \
    bf16x8 bv[4][2];                                                          \
    _Pragma("unroll")                                                         \
    for (int ks_ = 0; ks_ < 4; ++ks_) {                                       \
      bv[ks_][0] = *(const bf16x8*)(bp_ + ks_ * 16384);                       \
      bv[ks_][1] = *(const bf16x8*)(bp_ + ks_ * 16384 + 1024);                \
    }                                                                         \
    __builtin_amdgcn_s_setprio(1);                                            \
    _Pragma("unroll")                                                         \
    for (int rf_ = 0; rf_ < 2; ++rf_) {                                       \
      int rg_ = 2 * h + rf_;                                                  \
      _Pragma("unroll")                                                       \
      for (int ks_ = 0; ks_ < 4; ++ks_) {                                     \
        bf16x8 a_ = *(const bf16x8*)((AR) + (rg_ * 4 + ks_) * 1024 + slotR * 16); \
        acc[rf_][0] = __builtin_amdgcn_mfma_f32_16x16x32_bf16(a_, bv[ks_][0], acc[rf_][0], 0, 0, 0); \
        acc[rf_][1] = __builtin_amdgcn_mfma_f32_16x16x32_bf16(a_, bv[ks_][1], acc[rf_][1], 0, 0, 0); \
      }                                                                       \
    }                                                                         \
    __builtin_amdgcn_s_setprio(0);                                            \
  } while (0)

#define K3_TAIL                                                               \
  do {                                                                        \
    __builtin_amdgcn_sched_barrier(0);                                        \
    asm volatile("s_waitcnt lgkmcnt(0)" ::: "memory");                        \
    __builtin_amdgcn_s_barrier();                                             \
    __builtin_amdgcn_sched_barrier(0);                                        \
  } while (0)

  // Even waves: hv first, then MFMA.  Odd waves: MFMA first, then hv.
#define K3_ITER_H(S, AR, AW, STC, DO_HV)                                      \
  do {                                                                        \
    if (DO_HV) K3_HV(S, AW, STC);                                             \
    K3_LDA((S) + 3, STC);                                                     \
    K3_MFMA(S, AR);                                                           \
    K3_TAIL;                                                                  \
  } while (0)

#define K3_ITER_M(S, AR, AW, STC, DO_HV)                                      \
  do {                                                                        \
    K3_MFMA(S, AR);                                                           \
    if (DO_HV) K3_HV(S, AW, STC);                                             \
    K3_LDA((S) + 3, STC);                                                     \
    K3_TAIL;                                                                  \
  } while (0)

  // Prologue: adj(0) direct; adj(1)->st1, adj(2)->st0; A(0)->abuf0.
  int4 adj0a = *(const int4*)(adjrow);
  int4 adj0b = *(const int4*)(adjrow + 4);
  K3_LDA(1, st1);
  K3_LDA(2, st0);
  {
    float4 wq0 = *(const float4*)(wl);
    float4 wq1 = *(const float4*)(wl + 16);
    uint4 a0 = hv8(adj0a, adj0b, wq0, wq1, wh1, m, enm, zacc);
    *(uint4*)(abuf0 + aoff) = a0;
  }
  K3_TAIL;

  if ((wv & 1) == 0) {
    for (int s2 = 0; s2 < NSTEP - 2; s2 += 2) {
      K3_ITER_H(s2 + 0, abuf0, abuf1, st1, 1);
      K3_ITER_H(s2 + 1, abuf1, abuf0, st0, 1);
    }
    K3_ITER_H(NSTEP - 2, abuf0, abuf1, st1, 1);
    K3_ITER_H(NSTEP - 1, abuf1, abuf0, st0, 0);
  } else {
    for (int s2 = 0; s2 < NSTEP - 2; s2 += 2) {
      K3_ITER_M(s2 + 0, abuf0, abuf1, st1, 1);
      K3_ITER_M(s2 + 1, abuf1, abuf0, st0, 1);
    }
    K3_ITER_M(NSTEP - 2, abuf0, abuf1, st1, 1);
    K3_ITER_M(NSTEP - 1, abuf1, abuf0, st0, 0);
  }
#undef K3_ITER_H
#undef K3_ITER_M
#undef K3_TAIL
#undef K3_MFMA
#undef K3_HV
#undef K3_LDA

  // Z reduce over the 16 threads sharing row r0 (A-gen role).
  zacc += __shfl_xor(zacc, 1);
  zacc += __shfl_xor(zacc, 2);
  zacc += __shfl_xor(zacc, 4);
  zacc += __shfl_xor(zacc, 8);
  if ((t & 15) == 0) Zp[(size_t)kc * NR + iglob] = zacc;
#pragma unroll
  for (int rf = 0; rf < 2; ++rf)
#pragma unroll
    for (int un = 0; un < 2; ++un) {
      int f = (2 * g + un) * 16 + (lane & 15);
      int row0 = ibase + (2 * h + rf) * 16 + ((lane >> 4) << 2);
      size_t base = ((size_t)kc * NR + row0) * FOUT + f;
      PVp[base + 0 * FOUT] = acc[rf][un].x;
      PVp[base + 1 * FOUT] = acc[rf][un].y;
      PVp[base + 2 * FOUT] = acc[rf][un].z;
      PVp[base + 3 * FOUT] = acc[rf][un].w;
    }
}

// ---------------- k4: reduce 2 partials, normalize, relu ----------------
__global__ __launch_bounds__(256) void k4_reduce(const float* __restrict__ PVp,
                                                 const float* __restrict__ Zp,
                                                 float* __restrict__ out) {
  int tid = blockIdx.x * 256 + threadIdx.x;  // 0..524287
  int i = tid >> 6;
  int f4 = (tid & 63) * 4;
  float z = Zp[i] + Zp[NR + i];
  float4 p0 = *(const float4*)(PVp + (size_t)i * FOUT + f4);
  float4 p1 = *(const float4*)(PVp + ((size_t)NR + i) * FOUT + f4);
  float inv = 1.f / z;
  float4 r;
  r.x = fmaxf((p0.x + p1.x) * inv, 0.f);
  r.y = fmaxf((p0.y + p1.y) * inv, 0.f);
  r.z = fmaxf((p0.z + p1.z) * inv, 0.f);
  r.w = fmaxf((p0.w + p1.w) * inv, 0.f);
  *(float4*)(out + (size_t)i * FOUT + f4) = r;
}

// ---------------- launch ----------------
extern "C" void kernel_launch(void* const* d_in, const int* in_sizes, int n_in,
                              void* d_out, int out_size, void* d_ws,
                              size_t ws_size, hipStream_t stream) {
  const float* X = (const float*)d_in[0];
  const float* W = (const float*)d_in[1];
  const float* W2 = (const float*)d_in[2];
  const int* adj = (const int*)d_in[3];
  float* out = (float*)d_out;
  char* ws = (char*)d_ws;

  const size_t WHT_OFF = 0;                               // 4 MB fragment image
  const size_t WTBF_OFF = (size_t)4 * 1024 * 1024;        // 256 KB
  const size_t W1_OFF = WTBF_OFF + 256 * 1024;
  const size_t W2V_OFF = W1_OFF + 2048;
  const size_t WH1_OFF = W2V_OFF + 2048;
  const size_t WH2_OFF = WH1_OFF + 32768;
  const size_t MXK_OFF = WH2_OFF + 32768;
  const size_t ZP_OFF = MXK_OFF + 256;                    // float[2][8192]
  const size_t PV_OFF = ZP_OFF + (size_t)KSPLIT * NR * 4; // float[2][8192][256]

  char* WhTf = ws + WHT_OFF;
  char* WTbf = ws + WTBF_OFF;
  float* w1 = (float*)(ws + W1_OFF);
  float* w2 = (float*)(ws + W2V_OFF);
  float* Wh1 = (float*)(ws + WH1_OFF);
  float* Wh2 = (float*)(ws + WH2_OFF);
  unsigned* maxkey = (unsigned*)(ws + MXK_OFF);
  float* Zp = (float*)(ws + ZP_OFF);
  float* PVp = (float*)(ws + PV_OFF);

  k0_prep<<<128, 256, 0, stream>>>(W, W2, w1, w2, WTbf, maxkey);
  k2_fused<<<256, 256, 0, stream>>>(X, WTbf, w1, w2, WhTf, Wh1, Wh2, maxkey);
  k3_attn<<<256, 1024, 0, stream>>>(adj, WhTf, Wh1, Wh2, maxkey, PVp, Zp);
  k4_reduce<<<2048, 256, 0, stream>>>(PVp, Zp, out);
}

// Round 16
// 111.984 us; speedup vs baseline: 1.0842x; 1.0842x over previous
//
#include <hip/hip_runtime.h>
#include <cstdint>
#include <cstddef>

// GraphAttentionLayer: N=8192, IN=512, OUT=256
//  k0: w1=W@W2[:256], w2=W@W2[256:], WTbf = bf16(W^T) fragment image, maxkey=0
//  k2f: WhTf = bf16(X@W)^T fragment image + Wh1/Wh2 (exact fp32) + max
//  k3: fused (r14 = best-known: 1024 thr, IROWS=128, KSPLIT=4, 256 blocks,
//      wave remap g/h, B dbuf regs, lgkm-only barrier, wave-parity stagger)
//      + T5 s_setprio(1) around the MFMA cluster (stagger provides the wave
//      role-split setprio needs). NOTHING else changed vs r14 (109.1 us).
//  k4: reduce 4 partials, divide by Z, relu
#define NR 8192
#define FOUT 256
#define KIN 512
#define KSPLIT 4
#define JCHUNK (NR / KSPLIT)  // 2048
#define BKJ 64
#define NSTEP (JCHUNK / BKJ)  // 32
#define IROWS 128

typedef __attribute__((ext_vector_type(8))) short bf16x8;
typedef __attribute__((ext_vector_type(4))) float f32x4;

__device__ __forceinline__ unsigned f2bf(float x) {
  unsigned u = __float_as_uint(x);
  u += 0x7fffu + ((u >> 16) & 1u);
  return u >> 16;
}
__device__ __forceinline__ float bf2f(unsigned h) {
  return __uint_as_float(h << 16);
}
// monotone float<->uint key for atomicMax (0 == -inf sentinel)
__device__ __forceinline__ unsigned fkey(float x) {
  unsigned u = __float_as_uint(x);
  return (u & 0x80000000u) ? ~u : (u | 0x80000000u);
}
__device__ __forceinline__ float fkey_dec(unsigned k) {
  return __uint_as_float((k & 0x80000000u) ? (k ^ 0x80000000u) : ~k);
}

#define GLDS(g, l)                                                            \
  __builtin_amdgcn_global_load_lds(                                           \
      (const __attribute__((address_space(1))) unsigned int*)(g),             \
      (__attribute__((address_space(3))) unsigned int*)(l), 16, 0, 0)

// ---------------- k0: w1, w2, WTbf (B-fragment image), maxkey init ---------
__global__ __launch_bounds__(256) void k0_prep(const float* __restrict__ W,
                                               const float* __restrict__ W2,
                                               float* __restrict__ w1,
                                               float* __restrict__ w2,
                                               char* __restrict__ WTbf,
                                               unsigned* __restrict__ maxkey) {
  if (blockIdx.x == 0 && threadIdx.x == 0) *maxkey = 0u;
  int wv = threadIdx.x >> 6, lane = threadIdx.x & 63;
  int k = blockIdx.x * 4 + wv;  // 0..511
  int f4 = lane * 4;
  float4 wr = *(const float4*)(W + (size_t)k * FOUT + f4);
  float4 a = *(const float4*)(W2 + f4);
  float4 b = *(const float4*)(W2 + FOUT + f4);
  float d1 = wr.x * a.x + wr.y * a.y + wr.z * a.z + wr.w * a.w;
  float d2 = wr.x * b.x + wr.y * b.y + wr.z * b.z + wr.w * b.w;
#pragma unroll
  for (int off = 32; off; off >>= 1) {
    d1 += __shfl_xor(d1, off);
    d2 += __shfl_xor(d2, off);
  }
  if (lane == 0) {
    w1[k] = d1;
    w2[k] = d2;
  }
  int kt = k >> 5, kl = k & 31;
  float wv4[4] = {wr.x, wr.y, wr.z, wr.w};
#pragma unroll
  for (int ff = 0; ff < 4; ++ff) {
    int f = f4 + ff;
    size_t addr = (size_t)kt * 16384 + (f >> 4) * 1024 +
                  (((f & 15) | (((kl >> 3) & 3) << 4)) * 16) + (kl & 7) * 2;
    *(unsigned short*)(WTbf + addr) = (unsigned short)f2bf(wv4[ff]);
  }
}

// ---------------- k2f: WhTf fragment image + Wh1/Wh2 + maxkey --------------
__global__ __launch_bounds__(256) void k2_fused(
    const float* __restrict__ X, const char* __restrict__ WTbf,
    const float* __restrict__ w1, const float* __restrict__ w2,
    char* __restrict__ WhTf, float* __restrict__ Wh1, float* __restrict__ Wh2,
    unsigned* __restrict__ maxkey) {
  // [dbuf: 2 x (A 2KB + B 16KB)][w-slices 4KB]
  __shared__ char smem[2 * 18432 + 4096];
  char* buf0 = smem;
  char* buf1 = smem + 18432;
  char* wlds = smem + 2 * 18432;  // w1 floats [0,2048), w2 floats [2048,4096)
  int t = threadIdx.x, wv = t >> 6, lane = t & 63;
  int jb = blockIdx.x * 32;
  int jr = t >> 3, koff = (t & 7) * 4;
  int cA = (jr & 15) | (((koff >> 3) & 3) << 4);
  int swA = cA ^ (((cA >> 4) & 3) << 2);
  int aoff = (jr >> 4) * 1024 + swA * 16 + ((koff & 4) << 1);
  int slotR = lane ^ (((lane >> 4) & 3) << 2);
  const float* xrow = X + (size_t)(jb + jr) * KIN + koff;

  // Stage w1/w2 into LDS (reads via lgkm, so they don't pollute vmcnt).
  {
    float2 a_ = *(const float2*)(w1 + t * 2);
    float2 b_ = *(const float2*)(w2 + t * 2);
    *(float2*)(wlds + t * 8) = a_;
    *(float2*)(wlds + 2048 + t * 8) = b_;
  }
  __syncthreads();

  float4 st0, st1, st2, st3;
  float d1 = 0.f, d2 = 0.f;
  f32x4 acc[2][4];
#pragma unroll
  for (int a = 0; a < 2; ++a)
#pragma unroll
    for (int b = 0; b < 4; ++b) acc[a][b] = (f32x4){0.f, 0.f, 0.f, 0.f};

#define K2_GLB(KT, BUFW)                                                      \
  do {                                                                        \
    const char* gs_ = WTbf + ((size_t)(KT) << 14) + (wv << 12) + lane * 16;   \
    char* ld_ = (BUFW) + 2048 + (wv << 12);                                   \
    GLDS(gs_, ld_);                                                           \
    GLDS(gs_ + 1024, ld_ + 1024);                                             \
    GLDS(gs_ + 2048, ld_ + 2048);                                             \
    GLDS(gs_ + 3072, ld_ + 3072);                                             \
  } while (0)

#define K2_LDX(KT, ST) (ST) = *(const float4*)(xrow + (KT) * 32)

#define K2_AGEN(ST, BUFW, SNUM)                                               \
  do {                                                                        \
    uint2 a_;                                                                 \
    a_.x = f2bf((ST).x) | (f2bf((ST).y) << 16);                               \
    a_.y = f2bf((ST).z) | (f2bf((ST).w) << 16);                               \
    *(uint2*)((BUFW) + aoff) = a_;                                            \
    float4 wa_ = *(const float4*)(wlds + ((SNUM)*32 + koff) * 4);             \
    float4 wb_ = *(const float4*)(wlds + 2048 + ((SNUM)*32 + koff) * 4);      \
    d1 += (ST).x * wa_.x + (ST).y * wa_.y + (ST).z * wa_.z + (ST).w * wa_.w;  \
    d2 += (ST).x * wb_.x + (ST).y * wb_.y + (ST).z * wb_.z + (ST).w * wb_.w;  \
  } while (0)

#define K2_ITER(S, BUFR, BUFW, STC, STF)                                      \
  do {                                                                        \
    int s_ = (S);                                                             \
    if (s_ + 1 < 16) K2_GLB(s_ + 1, BUFW);                                    \
    K2_LDX((s_ + 3 < 16) ? s_ + 3 : 15, STF);                                 \
    if (s_ + 1 < 16) K2_AGEN(STC, BUFW, s_ + 1);                              \
    bf16x8 a0 = *(const bf16x8*)((BUFR) + slotR * 16);                        \
    bf16x8 a1 = *(const bf16x8*)((BUFR) + 1024 + slotR * 16);                 \
    bf16x8 b0 = *(const bf16x8*)((BUFR) + 2048 + (wv * 4 + 0) * 1024 + lane * 16); \
    bf16x8 b1 = *(const bf16x8*)((BUFR) + 2048 + (wv * 4 + 1) * 1024 + lane * 16); \
    bf16x8 b2 = *(const bf16x8*)((BUFR) + 2048 + (wv * 4 + 2) * 1024 + lane * 16); \
    bf16x8 b3 = *(const bf16x8*)((BUFR) + 2048 + (wv * 4 + 3) * 1024 + lane * 16); \
    acc[0][0] = __builtin_amdgcn_mfma_f32_16x16x32_bf16(a0, b0, acc[0][0], 0, 0, 0); \
    acc[0][1] = __builtin_amdgcn_mfma_f32_16x16x32_bf16(a0, b1, acc[0][1], 0, 0, 0); \
    acc[0][2] = __builtin_amdgcn_mfma_f32_16x16x32_bf16(a0, b2, acc[0][2], 0, 0, 0); \
    acc[0][3] = __builtin_amdgcn_mfma_f32_16x16x32_bf16(a0, b3, acc[0][3], 0, 0, 0); \
    acc[1][0] = __builtin_amdgcn_mfma_f32_16x16x32_bf16(a1, b0, acc[1][0], 0, 0, 0); \
    acc[1][1] = __builtin_amdgcn_mfma_f32_16x16x32_bf16(a1, b1, acc[1][1], 0, 0, 0); \
    acc[1][2] = __builtin_amdgcn_mfma_f32_16x16x32_bf16(a1, b2, acc[1][2], 0, 0, 0); \
    acc[1][3] = __builtin_amdgcn_mfma_f32_16x16x32_bf16(a1, b3, acc[1][3], 0, 0, 0); \
    __builtin_amdgcn_sched_barrier(0);                                        \
    asm volatile("s_waitcnt vmcnt(1)");                                       \
    asm volatile("s_waitcnt lgkmcnt(0)");                                     \
    __builtin_amdgcn_s_barrier();                                             \
    __builtin_amdgcn_sched_barrier(0);                                        \
  } while (0)

  // Prologue
  K2_GLB(0, buf0);
  K2_LDX(0, st0);
  K2_LDX(1, st1);
  K2_LDX(2, st2);
  K2_AGEN(st0, buf0, 0);
  __builtin_amdgcn_sched_barrier(0);
  asm volatile("s_waitcnt vmcnt(2)");
  asm volatile("s_waitcnt lgkmcnt(0)");
  __builtin_amdgcn_s_barrier();
  __builtin_amdgcn_sched_barrier(0);

  for (int s4 = 0; s4 < 16; s4 += 4) {
    K2_ITER(s4 + 0, buf0, buf1, st1, st3);
    K2_ITER(s4 + 1, buf1, buf0, st2, st0);
    K2_ITER(s4 + 2, buf0, buf1, st3, st1);
    K2_ITER(s4 + 3, buf1, buf0, st0, st2);
  }
#undef K2_ITER
#undef K2_AGEN
#undef K2_LDX
#undef K2_GLB

  // Epilogue A: fragment image for this 32-j tile into buf0 B-area, copy out.
  int q = lane >> 4;
#pragma unroll
  for (int mi = 0; mi < 2; ++mi)
#pragma unroll
    for (int nn = 0; nn < 4; ++nn) {
      int u2 = wv * 4 + nn;
      int cell = (lane & 15) | ((((mi * 2) + (q >> 1)) & 3) << 4);
      uint2 v;
      v.x = f2bf(acc[mi][nn].x) | (f2bf(acc[mi][nn].y) << 16);
      v.y = f2bf(acc[mi][nn].z) | (f2bf(acc[mi][nn].w) << 16);
      *(uint2*)(buf0 + 2048 + u2 * 1024 + cell * 16 + ((q & 1) << 3)) = v;
    }
  __syncthreads();
  char* wb = WhTf + (size_t)blockIdx.x * 16384;
#pragma unroll
  for (int q2 = 0; q2 < 4; ++q2) {
    uint4 v = *(const uint4*)(buf0 + 2048 + q2 * 4096 + t * 16);
    *(uint4*)(wb + q2 * 4096 + t * 16) = v;
  }

  // Epilogue B: reduce Wh1/Wh2 over the 8 lanes sharing row jr, write, max.
  d1 += __shfl_xor(d1, 1);
  d1 += __shfl_xor(d1, 2);
  d1 += __shfl_xor(d1, 4);
  d2 += __shfl_xor(d2, 1);
  d2 += __shfl_xor(d2, 2);
  d2 += __shfl_xor(d2, 4);
  if ((t & 7) == 0) {
    Wh1[jb + jr] = d1;
    Wh2[jb + jr] = d2;
  }
  float mx = d2;
#pragma unroll
  for (int off = 32; off >= 8; off >>= 1) mx = fmaxf(mx, __shfl_xor(mx, off));
  __shared__ float red[4];
  if (lane == 0) red[wv] = mx;
  __syncthreads();
  if (t == 0) {
    float bm = fmaxf(fmaxf(red[0], red[1]), fmaxf(red[2], red[3]));
    atomicMax(maxkey, fkey(bm));
  }
}

// ---------------- k3: fused attention weights + PV matmul ----------------
__device__ __forceinline__ uint2 hv4(int4 aq, float4 wq, float wh1, float m,
                                     float enm, float& z) {
  float s0 = wh1 + wq.x, s1 = wh1 + wq.y, s2 = wh1 + wq.z, s3 = wh1 + wq.w;
  s0 = fmaxf(s0, 0.2f * s0);
  s1 = fmaxf(s1, 0.2f * s1);
  s2 = fmaxf(s2, 0.2f * s2);
  s3 = fmaxf(s3, 0.2f * s3);
  float w0 = aq.x > 0 ? __expf(s0 - m) : enm;
  float w1 = aq.y > 0 ? __expf(s1 - m) : enm;
  float w2 = aq.z > 0 ? __expf(s2 - m) : enm;
  float w3 = aq.w > 0 ? __expf(s3 - m) : enm;
  unsigned h0 = f2bf(w0), h1 = f2bf(w1), h2 = f2bf(w2), h3 = f2bf(w3);
  z += bf2f(h0) + bf2f(h1) + bf2f(h2) + bf2f(h3);
  uint2 r;
  r.x = h0 | (h1 << 16);
  r.y = h2 | (h3 << 16);
  return r;
}
__device__ __forceinline__ uint4 hv8(int4 a0, int4 a1, float4 w0, float4 w1,
                                     float wh1, float m, float enm, float& z) {
  uint2 r0 = hv4(a0, w0, wh1, m, enm, z);
  uint2 r1 = hv4(a1, w1, wh1, m, enm, z);
  return (uint4){r0.x, r0.y, r1.x, r1.y};
}

__global__ __launch_bounds__(1024, 4) void k3_attn(
    const int* __restrict__ adj, const char* __restrict__ WhTf,
    const float* __restrict__ Wh1, const float* __restrict__ Wh2,
    const unsigned* __restrict__ maxptr, float* __restrict__ PVp,
    float* __restrict__ Zp) {
  // [A dbuf 2 x 16KB][wh2 chunk 8KB] = 40960 B
  __shared__ char smem[40960];
  char* abuf0 = smem;
  char* abuf1 = smem + 16384;
  char* wlds = smem + 32768;
  int t = threadIdx.x, wv = t >> 6, lane = t & 63;
  int kc = blockIdx.x & 3;
  int ib = blockIdx.x >> 2;  // 0..63
  int ibase = ib * IROWS;
  int jbch = kc * JCHUNK;
  int r0 = t >> 3;           // row in tile 0..127 (A-gen role)
  int j8 = (t & 7) * 8;      // j offset 0..56
  int iglob = ibase + r0;
  float maxwh2 = fkey_dec(*maxptr);
  float wh1 = Wh1[iglob];
  float m = fmaxf(0.f, wh1 + maxwh2);
  float enm = __expf(-m);
  // A-image: unit = (r0>>4)*2 + (j8>>5); cell swizzled.
  int unitA = (r0 >> 4) * 2 + (j8 >> 5);
  int cA = (r0 & 15) | (((j8 & 31) >> 3) << 4);
  int swA = cA ^ (((cA >> 4) & 3) << 2);
  int aoff = unitA * 1024 + swA * 16;
  int slotR = lane ^ (((lane >> 4) & 3) << 2);
  const int* adjrow = adj + ((size_t)iglob << 13) + jbch + j8;
  // MFMA role: wave (g = wv>>1, h = wv&1) owns f-units {2g,2g+1} and
  // row-blocks {4h..4h+3}. Each A-frag feeds 2 MFMAs (un=0,1).
  int g = wv >> 1, h = wv & 1;
  const char* bbase = WhTf + ((size_t)(kc * 64) << 14) + (size_t)(2 * g) * 1024 +
                      (size_t)lane * 16;
  const char* wl = wlds + j8 * 4;

  // Stage this chunk's Wh2 (2048 floats = 8KB) into LDS once.
  *(float2*)(wlds + t * 8) = *(const float2*)(Wh2 + jbch + t * 2);
  __syncthreads();

  // B regs: [un][ks], double-buffered (bA = even iters, bB = odd).
  bf16x8 bA00, bA01, bA10, bA11, bB00, bB01, bB10, bB11;
  int4 st0_a, st0_b, st1_a, st1_b;
  f32x4 acc[4][2];
#pragma unroll
  for (int a = 0; a < 4; ++a)
#pragma unroll
    for (int b = 0; b < 2; ++b) acc[a][b] = (f32x4){0.f, 0.f, 0.f, 0.f};
  float zacc = 0.f;

#define K3_LDB(S, B00, B01, B10, B11)                                         \
  do {                                                                        \
    int sc_ = (S) < NSTEP ? (S) : NSTEP - 1;                                  \
    const char* bp_ = bbase + (size_t)(2 * sc_) * 16384;                      \
    B00 = *(const bf16x8*)(bp_);                 /* un0 ks0 */                \
    B01 = *(const bf16x8*)(bp_ + 16384);         /* un0 ks1 */                \
    B10 = *(const bf16x8*)(bp_ + 1024);          /* un1 ks0 */                \
    B11 = *(const bf16x8*)(bp_ + 16384 + 1024);  /* un1 ks1 */                \
  } while (0)

#define K3_LDA(S, ST)                                                         \
  do {                                                                        \
    int sc_ = (S) < NSTEP ? (S) : NSTEP - 1;                                  \
    ST##_a = *(const int4*)(adjrow + sc_ * BKJ);                              \
    ST##_b = *(const int4*)(adjrow + sc_ * BKJ + 4);                          \
  } while (0)

#define K3_HV(S, AW, STC)                                                     \
  do {                                                                        \
    float4 wq0_ = *(const float4*)(wl + ((S) + 1) * 256);                     \
    float4 wq1_ = *(const float4*)(wl + ((S) + 1) * 256 + 16);                \
    uint4 a_ = hv8(STC##_a, STC##_b, wq0_, wq1_, wh1, m, enm, zacc);          \
    *(uint4*)((AW) + aoff) = a_;                                              \
  } while (0)

#define K3_MFMA(AR, BC00, BC01, BC10, BC11)                                   \
  do {                                                                        \
    __builtin_amdgcn_s_setprio(1);                                            \
    _Pragma("unroll")                                                         \
    for (int rf_ = 0; rf_ < 4; ++rf_) {                                       \
      int ub_ = (h * 4 + rf_) * 2;                                            \
      bf16x8 a0_ = *(const bf16x8*)((AR) + (ub_ + 0) * 1024 + slotR * 16);    \
      bf16x8 a1_ = *(const bf16x8*)((AR) + (ub_ + 1) * 1024 + slotR * 16);    \
      acc[rf_][0] = __builtin_amdgcn_mfma_f32_16x16x32_bf16(a0_, BC00, acc[rf_][0], 0, 0, 0); \
      acc[rf_][1] = __builtin_amdgcn_mfma_f32_16x16x32_bf16(a0_, BC10, acc[rf_][1], 0, 0, 0); \
      acc[rf_][0] = __builtin_amdgcn_mfma_f32_16x16x32_bf16(a1_, BC01, acc[rf_][0], 0, 0, 0); \
      acc[rf_][1] = __builtin_amdgcn_mfma_f32_16x16x32_bf16(a1_, BC11, acc[rf_][1], 0, 0, 0); \
    }                                                                         \
    __builtin_amdgcn_s_setprio(0);                                            \
  } while (0)

#define K3_TAIL                                                               \
  do {                                                                        \
    __builtin_amdgcn_sched_barrier(0);                                        \
    asm volatile("s_waitcnt lgkmcnt(0)" ::: "memory");                        \
    __builtin_amdgcn_s_barrier();                                             \
    __builtin_amdgcn_sched_barrier(0);                                        \
  } while (0)

  // Even waves: hv first, then MFMA.  Odd waves: MFMA first, then hv.
#define K3_ITER_H(S, AR, AW, BC00, BC01, BC10, BC11, BF00, BF01, BF10, BF11,  \
                  STC, DO_HV)                                                 \
  do {                                                                        \
    int s_ = (S);                                                             \
    K3_LDB(s_ + 1, BF00, BF01, BF10, BF11);                                   \
    if (DO_HV) K3_HV(s_, AW, STC);                                            \
    K3_LDA(s_ + 3, STC);                                                      \
    K3_MFMA(AR, BC00, BC01, BC10, BC11);                                      \
    K3_TAIL;                                                                  \
  } while (0)

#define K3_ITER_M(S, AR, AW, BC00, BC01, BC10, BC11, BF00, BF01, BF10, BF11,  \
                  STC, DO_HV)                                                 \
  do {                                                                        \
    int s_ = (S);                                                             \
    K3_LDB(s_ + 1, BF00, BF01, BF10, BF11);                                   \
    K3_MFMA(AR, BC00, BC01, BC10, BC11);                                      \
    if (DO_HV) K3_HV(s_, AW, STC);                                            \
    K3_LDA(s_ + 3, STC);                                                      \
    K3_TAIL;                                                                  \
  } while (0)

  // Prologue: B(0)->bA; adj(0) direct; adj(1)->st1, adj(2)->st0; A(0)->abuf0.
  K3_LDB(0, bA00, bA01, bA10, bA11);
  int4 adj0a = *(const int4*)(adjrow);
  int4 adj0b = *(const int4*)(adjrow + 4);
  K3_LDA(1, st1);
  K3_LDA(2, st0);
  {
    float4 wq0 = *(const float4*)(wl);
    float4 wq1 = *(const float4*)(wl + 16);
    uint4 a0 = hv8(adj0a, adj0b, wq0, wq1, wh1, m, enm, zacc);
    *(uint4*)(abuf0 + aoff) = a0;
  }
  K3_TAIL;

  if ((wv & 1) == 0) {
    for (int s2 = 0; s2 < NSTEP - 2; s2 += 2) {
      K3_ITER_H(s2 + 0, abuf0, abuf1, bA00, bA01, bA10, bA11, bB00, bB01,
                bB10, bB11, st1, 1);
      K3_ITER_H(s2 + 1, abuf1, abuf0, bB00, bB01, bB10, bB11, bA00, bA01,
                bA10, bA11, st0, 1);
    }
    K3_ITER_H(NSTEP - 2, abuf0, abuf1, bA00, bA01, bA10, bA11, bB00, bB01,
              bB10, bB11, st1, 1);
    K3_ITER_H(NSTEP - 1, abuf1, abuf0, bB00, bB01, bB10, bB11, bA00, bA01,
              bA10, bA11, st0, 0);
  } else {
    for (int s2 = 0; s2 < NSTEP - 2; s2 += 2) {
      K3_ITER_M(s2 + 0, abuf0, abuf1, bA00, bA01, bA10, bA11, bB00, bB01,
                bB10, bB11, st1, 1);
      K3_ITER_M(s2 + 1, abuf1, abuf0, bB00, bB01, bB10, bB11, bA00, bA01,
                bA10, bA11, st0, 1);
    }
    K3_ITER_M(NSTEP - 2, abuf0, abuf1, bA00, bA01, bA10, bA11, bB00, bB01,
              bB10, bB11, st1, 1);
    K3_ITER_M(NSTEP - 1, abuf1, abuf0, bB00, bB01, bB10, bB11, bA00, bA01,
              bA10, bA11, st0, 0);
  }
#undef K3_ITER_H
#undef K3_ITER_M
#undef K3_TAIL
#undef K3_MFMA
#undef K3_HV
#undef K3_LDA
#undef K3_LDB

  // Z reduce over the 8 threads sharing row r0 (A-gen role).
  zacc += __shfl_xor(zacc, 1);
  zacc += __shfl_xor(zacc, 2);
  zacc += __shfl_xor(zacc, 4);
  if ((t & 7) == 0) Zp[(size_t)kc * NR + iglob] = zacc;
#pragma unroll
  for (int rf = 0; rf < 4; ++rf)
#pragma unroll
    for (int un = 0; un < 2; ++un) {
      int f = (2 * g + un) * 16 + (lane & 15);
      int row0 = ibase + (h * 4 + rf) * 16 + ((lane >> 4) << 2);
      size_t base = ((size_t)kc * NR + row0) * FOUT + f;
      PVp[base + 0 * FOUT] = acc[rf][un].x;
      PVp[base + 1 * FOUT] = acc[rf][un].y;
      PVp[base + 2 * FOUT] = acc[rf][un].z;
      PVp[base + 3 * FOUT] = acc[rf][un].w;
    }
}

// ---------------- k4: reduce partials, normalize, relu ----------------
__global__ __launch_bounds__(256) void k4_reduce(const float* __restrict__ PVp,
                                                 const float* __restrict__ Zp,
                                                 float* __restrict__ out) {
  int tid = blockIdx.x * 256 + threadIdx.x;  // 0..524287
  int i = tid >> 6;
  int f4 = (tid & 63) * 4;
  float z = Zp[i] + Zp[NR + i] + Zp[2 * NR + i] + Zp[3 * NR + i];
  float4 a = {0.f, 0.f, 0.f, 0.f};
#pragma unroll
  for (int c = 0; c < KSPLIT; ++c) {
    float4 p = *(const float4*)(PVp + ((size_t)c * NR + i) * FOUT + f4);
    a.x += p.x;
    a.y += p.y;
    a.z += p.z;
    a.w += p.w;
  }
  float inv = 1.f / z;
  float4 r;
  r.x = fmaxf(a.x * inv, 0.f);
  r.y = fmaxf(a.y * inv, 0.f);
  r.z = fmaxf(a.z * inv, 0.f);
  r.w = fmaxf(a.w * inv, 0.f);
  *(float4*)(out + (size_t)i * FOUT + f4) = r;
}

// ---------------- launch ----------------
extern "C" void kernel_launch(void* const* d_in, const int* in_sizes, int n_in,
                              void* d_out, int out_size, void* d_ws,
                              size_t ws_size, hipStream_t stream) {
  const float* X = (const float*)d_in[0];
  const float* W = (const float*)d_in[1];
  const float* W2 = (const float*)d_in[2];
  const int* adj = (const int*)d_in[3];
  float* out = (float*)d_out;
  char* ws = (char*)d_ws;

  const size_t WHT_OFF = 0;                               // 4 MB fragment image
  const size_t WTBF_OFF = (size_t)4 * 1024 * 1024;        // 256 KB
  const size_t W1_OFF = WTBF_OFF + 256 * 1024;
  const size_t W2V_OFF = W1_OFF + 2048;
  const size_t WH1_OFF = W2V_OFF + 2048;
  const size_t WH2_OFF = WH1_OFF + 32768;
  const size_t MXK_OFF = WH2_OFF + 32768;
  const size_t ZP_OFF = MXK_OFF + 256;                    // float[4][8192]
  const size_t PV_OFF = ZP_OFF + (size_t)KSPLIT * NR * 4; // float[4][8192][256]

  char* WhTf = ws + WHT_OFF;
  char* WTbf = ws + WTBF_OFF;
  float* w1 = (float*)(ws + W1_OFF);
  float* w2 = (float*)(ws + W2V_OFF);
  float* Wh1 = (float*)(ws + WH1_OFF);
  float* Wh2 = (float*)(ws + WH2_OFF);
  unsigned* maxkey = (unsigned*)(ws + MXK_OFF);
  float* Zp = (float*)(ws + ZP_OFF);
  float* PVp = (float*)(ws + PV_OFF);

  k0_prep<<<128, 256, 0, stream>>>(W, W2, w1, w2, WTbf, maxkey);
  k2_fused<<<256, 256, 0, stream>>>(X, WTbf, w1, w2, WhTf, Wh1, Wh2, maxkey);
  k3_attn<<<256, 1024, 0, stream>>>(adj, WhTf, Wh1, Wh2, maxkey, PVp, Zp);
  k4_reduce<<<2048, 256, 0, stream>>>(PVp, Zp, out);
}

// Round 17
// 106.820 us; speedup vs baseline: 1.1366x; 1.0483x over previous
//
#include <hip/hip_runtime.h>
#include <hip/hip_bf16.h>
#include <cstdint>
#include <cstddef>

// GraphAttentionLayer: N=8192, IN=512, OUT=256
//  k0: w1=W@W2[:256], w2=W@W2[256:], WTbf = bf16(W^T) fragment image, maxkey=0
//  k2f: WhTf = bf16(X@W)^T fragment image + Wh1/Wh2 (exact fp32) + max
//  k3: fused (r14 = best-known: 1024 thr, IROWS=128, KSPLIT=4, 256 blocks,
//      wave remap g/h, B dbuf regs, lgkm-only barrier, wave-parity stagger).
//      A/B vs r14: hv uses NATIVE bf16 casts (compiler emits v_cvt_pk_bf16_f32;
//      identical RNE rounding -> bitwise-same results). No setprio (r16 null).
//  k4: reduce 4 partials, divide by Z, relu
#define NR 8192
#define FOUT 256
#define KIN 512
#define KSPLIT 4
#define JCHUNK (NR / KSPLIT)  // 2048
#define BKJ 64
#define NSTEP (JCHUNK / BKJ)  // 32
#define IROWS 128

typedef __attribute__((ext_vector_type(8))) short bf16x8;
typedef __attribute__((ext_vector_type(4))) float f32x4;

__device__ __forceinline__ unsigned f2bf(float x) {
  unsigned u = __float_as_uint(x);
  u += 0x7fffu + ((u >> 16) & 1u);
  return u >> 16;
}
// native-cast versions for the k3 hot path (same RNE rounding, compiler can
// fuse pairs into v_cvt_pk_bf16_f32)
__device__ __forceinline__ unsigned f2bf_n(float x) {
  __hip_bfloat16 b = __float2bfloat16(x);
  unsigned short us;
  __builtin_memcpy(&us, &b, 2);
  return (unsigned)us;
}
__device__ __forceinline__ float bf2f_n(unsigned h) {
  unsigned short us = (unsigned short)h;
  __hip_bfloat16 b;
  __builtin_memcpy(&b, &us, 2);
  return __bfloat162float(b);
}
// monotone float<->uint key for atomicMax (0 == -inf sentinel)
__device__ __forceinline__ unsigned fkey(float x) {
  unsigned u = __float_as_uint(x);
  return (u & 0x80000000u) ? ~u : (u | 0x80000000u);
}
__device__ __forceinline__ float fkey_dec(unsigned k) {
  return __uint_as_float((k & 0x80000000u) ? (k ^ 0x80000000u) : ~k);
}

#define GLDS(g, l)                                                            \
  __builtin_amdgcn_global_load_lds(                                           \
      (const __attribute__((address_space(1))) unsigned int*)(g),             \
      (__attribute__((address_space(3))) unsigned int*)(l), 16, 0, 0)

// ---------------- k0: w1, w2, WTbf (B-fragment image), maxkey init ---------
__global__ __launch_bounds__(256) void k0_prep(const float* __restrict__ W,
                                               const float* __restrict__ W2,
                                               float* __restrict__ w1,
                                               float* __restrict__ w2,
                                               char* __restrict__ WTbf,
                                               unsigned* __restrict__ maxkey) {
  if (blockIdx.x == 0 && threadIdx.x == 0) *maxkey = 0u;
  int wv = threadIdx.x >> 6, lane = threadIdx.x & 63;
  int k = blockIdx.x * 4 + wv;  // 0..511
  int f4 = lane * 4;
  float4 wr = *(const float4*)(W + (size_t)k * FOUT + f4);
  float4 a = *(const float4*)(W2 + f4);
  float4 b = *(const float4*)(W2 + FOUT + f4);
  float d1 = wr.x * a.x + wr.y * a.y + wr.z * a.z + wr.w * a.w;
  float d2 = wr.x * b.x + wr.y * b.y + wr.z * b.z + wr.w * b.w;
#pragma unroll
  for (int off = 32; off; off >>= 1) {
    d1 += __shfl_xor(d1, off);
    d2 += __shfl_xor(d2, off);
  }
  if (lane == 0) {
    w1[k] = d1;
    w2[k] = d2;
  }
  int kt = k >> 5, kl = k & 31;
  float wv4[4] = {wr.x, wr.y, wr.z, wr.w};
#pragma unroll
  for (int ff = 0; ff < 4; ++ff) {
    int f = f4 + ff;
    size_t addr = (size_t)kt * 16384 + (f >> 4) * 1024 +
                  (((f & 15) | (((kl >> 3) & 3) << 4)) * 16) + (kl & 7) * 2;
    *(unsigned short*)(WTbf + addr) = (unsigned short)f2bf(wv4[ff]);
  }
}

// ---------------- k2f: WhTf fragment image + Wh1/Wh2 + maxkey --------------
__global__ __launch_bounds__(256) void k2_fused(
    const float* __restrict__ X, const char* __restrict__ WTbf,
    const float* __restrict__ w1, const float* __restrict__ w2,
    char* __restrict__ WhTf, float* __restrict__ Wh1, float* __restrict__ Wh2,
    unsigned* __restrict__ maxkey) {
  // [dbuf: 2 x (A 2KB + B 16KB)][w-slices 4KB]
  __shared__ char smem[2 * 18432 + 4096];
  char* buf0 = smem;
  char* buf1 = smem + 18432;
  char* wlds = smem + 2 * 18432;  // w1 floats [0,2048), w2 floats [2048,4096)
  int t = threadIdx.x, wv = t >> 6, lane = t & 63;
  int jb = blockIdx.x * 32;
  int jr = t >> 3, koff = (t & 7) * 4;
  int cA = (jr & 15) | (((koff >> 3) & 3) << 4);
  int swA = cA ^ (((cA >> 4) & 3) << 2);
  int aoff = (jr >> 4) * 1024 + swA * 16 + ((koff & 4) << 1);
  int slotR = lane ^ (((lane >> 4) & 3) << 2);
  const float* xrow = X + (size_t)(jb + jr) * KIN + koff;

  // Stage w1/w2 into LDS (reads via lgkm, so they don't pollute vmcnt).
  {
    float2 a_ = *(const float2*)(w1 + t * 2);
    float2 b_ = *(const float2*)(w2 + t * 2);
    *(float2*)(wlds + t * 8) = a_;
    *(float2*)(wlds + 2048 + t * 8) = b_;
  }
  __syncthreads();

  float4 st0, st1, st2, st3;
  float d1 = 0.f, d2 = 0.f;
  f32x4 acc[2][4];
#pragma unroll
  for (int a = 0; a < 2; ++a)
#pragma unroll
    for (int b = 0; b < 4; ++b) acc[a][b] = (f32x4){0.f, 0.f, 0.f, 0.f};

#define K2_GLB(KT, BUFW)                                                      \
  do {                                                                        \
    const char* gs_ = WTbf + ((size_t)(KT) << 14) + (wv << 12) + lane * 16;   \
    char* ld_ = (BUFW) + 2048 + (wv << 12);                                   \
    GLDS(gs_, ld_);                                                           \
    GLDS(gs_ + 1024, ld_ + 1024);                                             \
    GLDS(gs_ + 2048, ld_ + 2048);                                             \
    GLDS(gs_ + 3072, ld_ + 3072);                                             \
  } while (0)

#define K2_LDX(KT, ST) (ST) = *(const float4*)(xrow + (KT) * 32)

#define K2_AGEN(ST, BUFW, SNUM)                                               \
  do {                                                                        \
    uint2 a_;                                                                 \
    a_.x = f2bf((ST).x) | (f2bf((ST).y) << 16);                               \
    a_.y = f2bf((ST).z) | (f2bf((ST).w) << 16);                               \
    *(uint2*)((BUFW) + aoff) = a_;                                            \
    float4 wa_ = *(const float4*)(wlds + ((SNUM)*32 + koff) * 4);             \
    float4 wb_ = *(const float4*)(wlds + 2048 + ((SNUM)*32 + koff) * 4);      \
    d1 += (ST).x * wa_.x + (ST).y * wa_.y + (ST).z * wa_.z + (ST).w * wa_.w;  \
    d2 += (ST).x * wb_.x + (ST).y * wb_.y + (ST).z * wb_.z + (ST).w * wb_.w;  \
  } while (0)

#define K2_ITER(S, BUFR, BUFW, STC, STF)                                      \
  do {                                                                        \
    int s_ = (S);                                                             \
    if (s_ + 1 < 16) K2_GLB(s_ + 1, BUFW);                                    \
    K2_LDX((s_ + 3 < 16) ? s_ + 3 : 15, STF);                                 \
    if (s_ + 1 < 16) K2_AGEN(STC, BUFW, s_ + 1);                              \
    bf16x8 a0 = *(const bf16x8*)((BUFR) + slotR * 16);                        \
    bf16x8 a1 = *(const bf16x8*)((BUFR) + 1024 + slotR * 16);                 \
    bf16x8 b0 = *(const bf16x8*)((BUFR) + 2048 + (wv * 4 + 0) * 1024 + lane * 16); \
    bf16x8 b1 = *(const bf16x8*)((BUFR) + 2048 + (wv * 4 + 1) * 1024 + lane * 16); \
    bf16x8 b2 = *(const bf16x8*)((BUFR) + 2048 + (wv * 4 + 2) * 1024 + lane * 16); \
    bf16x8 b3 = *(const bf16x8*)((BUFR) + 2048 + (wv * 4 + 3) * 1024 + lane * 16); \
    acc[0][0] = __builtin_amdgcn_mfma_f32_16x16x32_bf16(a0, b0, acc[0][0], 0, 0, 0); \
    acc[0][1] = __builtin_amdgcn_mfma_f32_16x16x32_bf16(a0, b1, acc[0][1], 0, 0, 0); \
    acc[0][2] = __builtin_amdgcn_mfma_f32_16x16x32_bf16(a0, b2, acc[0][2], 0, 0, 0); \
    acc[0][3] = __builtin_amdgcn_mfma_f32_16x16x32_bf16(a0, b3, acc[0][3], 0, 0, 0); \
    acc[1][0] = __builtin_amdgcn_mfma_f32_16x16x32_bf16(a1, b0, acc[1][0], 0, 0, 0); \
    acc[1][1] = __builtin_amdgcn_mfma_f32_16x16x32_bf16(a1, b1, acc[1][1], 0, 0, 0); \
    acc[1][2] = __builtin_amdgcn_mfma_f32_16x16x32_bf16(a1, b2, acc[1][2], 0, 0, 0); \
    acc[1][3] = __builtin_amdgcn_mfma_f32_16x16x32_bf16(a1, b3, acc[1][3], 0, 0, 0); \
    __builtin_amdgcn_sched_barrier(0);                                        \
    asm volatile("s_waitcnt vmcnt(1)");                                       \
    asm volatile("s_waitcnt lgkmcnt(0)");                                     \
    __builtin_amdgcn_s_barrier();                                             \
    __builtin_amdgcn_sched_barrier(0);                                        \
  } while (0)

  // Prologue
  K2_GLB(0, buf0);
  K2_LDX(0, st0);
  K2_LDX(1, st1);
  K2_LDX(2, st2);
  K2_AGEN(st0, buf0, 0);
  __builtin_amdgcn_sched_barrier(0);
  asm volatile("s_waitcnt vmcnt(2)");
  asm volatile("s_waitcnt lgkmcnt(0)");
  __builtin_amdgcn_s_barrier();
  __builtin_amdgcn_sched_barrier(0);

  for (int s4 = 0; s4 < 16; s4 += 4) {
    K2_ITER(s4 + 0, buf0, buf1, st1, st3);
    K2_ITER(s4 + 1, buf1, buf0, st2, st0);
    K2_ITER(s4 + 2, buf0, buf1, st3, st1);
    K2_ITER(s4 + 3, buf1, buf0, st0, st2);
  }
#undef K2_ITER
#undef K2_AGEN
#undef K2_LDX
#undef K2_GLB

  // Epilogue A: fragment image for this 32-j tile into buf0 B-area, copy out.
  int q = lane >> 4;
#pragma unroll
  for (int mi = 0; mi < 2; ++mi)
#pragma unroll
    for (int nn = 0; nn < 4; ++nn) {
      int u2 = wv * 4 + nn;
      int cell = (lane & 15) | ((((mi * 2) + (q >> 1)) & 3) << 4);
      uint2 v;
      v.x = f2bf(acc[mi][nn].x) | (f2bf(acc[mi][nn].y) << 16);
      v.y = f2bf(acc[mi][nn].z) | (f2bf(acc[mi][nn].w) << 16);
      *(uint2*)(buf0 + 2048 + u2 * 1024 + cell * 16 + ((q & 1) << 3)) = v;
    }
  __syncthreads();
  char* wb = WhTf + (size_t)blockIdx.x * 16384;
#pragma unroll
  for (int q2 = 0; q2 < 4; ++q2) {
    uint4 v = *(const uint4*)(buf0 + 2048 + q2 * 4096 + t * 16);
    *(uint4*)(wb + q2 * 4096 + t * 16) = v;
  }

  // Epilogue B: reduce Wh1/Wh2 over the 8 lanes sharing row jr, write, max.
  d1 += __shfl_xor(d1, 1);
  d1 += __shfl_xor(d1, 2);
  d1 += __shfl_xor(d1, 4);
  d2 += __shfl_xor(d2, 1);
  d2 += __shfl_xor(d2, 2);
  d2 += __shfl_xor(d2, 4);
  if ((t & 7) == 0) {
    Wh1[jb + jr] = d1;
    Wh2[jb + jr] = d2;
  }
  float mx = d2;
#pragma unroll
  for (int off = 32; off >= 8; off >>= 1) mx = fmaxf(mx, __shfl_xor(mx, off));
  __shared__ float red[4];
  if (lane == 0) red[wv] = mx;
  __syncthreads();
  if (t == 0) {
    float bm = fmaxf(fmaxf(red[0], red[1]), fmaxf(red[2], red[3]));
    atomicMax(maxkey, fkey(bm));
  }
}

// ---------------- k3: fused attention weights + PV matmul ----------------
__device__ __forceinline__ uint2 hv4(int4 aq, float4 wq, float wh1, float m,
                                     float enm, float& z) {
  float s0 = wh1 + wq.x, s1 = wh1 + wq.y, s2 = wh1 + wq.z, s3 = wh1 + wq.w;
  s0 = fmaxf(s0, 0.2f * s0);
  s1 = fmaxf(s1, 0.2f * s1);
  s2 = fmaxf(s2, 0.2f * s2);
  s3 = fmaxf(s3, 0.2f * s3);
  float w0 = aq.x > 0 ? __expf(s0 - m) : enm;
  float w1 = aq.y > 0 ? __expf(s1 - m) : enm;
  float w2 = aq.z > 0 ? __expf(s2 - m) : enm;
  float w3 = aq.w > 0 ? __expf(s3 - m) : enm;
  unsigned h0 = f2bf_n(w0), h1 = f2bf_n(w1), h2 = f2bf_n(w2), h3 = f2bf_n(w3);
  z += bf2f_n(h0) + bf2f_n(h1) + bf2f_n(h2) + bf2f_n(h3);
  uint2 r;
  r.x = h0 | (h1 << 16);
  r.y = h2 | (h3 << 16);
  return r;
}
__device__ __forceinline__ uint4 hv8(int4 a0, int4 a1, float4 w0, float4 w1,
                                     float wh1, float m, float enm, float& z) {
  uint2 r0 = hv4(a0, w0, wh1, m, enm, z);
  uint2 r1 = hv4(a1, w1, wh1, m, enm, z);
  return (uint4){r0.x, r0.y, r1.x, r1.y};
}

__global__ __launch_bounds__(1024, 4) void k3_attn(
    const int* __restrict__ adj, const char* __restrict__ WhTf,
    const float* __restrict__ Wh1, const float* __restrict__ Wh2,
    const unsigned* __restrict__ maxptr, float* __restrict__ PVp,
    float* __restrict__ Zp) {
  // [A dbuf 2 x 16KB][wh2 chunk 8KB] = 40960 B
  __shared__ char smem[40960];
  char* abuf0 = smem;
  char* abuf1 = smem + 16384;
  char* wlds = smem + 32768;
  int t = threadIdx.x, wv = t >> 6, lane = t & 63;
  int kc = blockIdx.x & 3;
  int ib = blockIdx.x >> 2;  // 0..63
  int ibase = ib * IROWS;
  int jbch = kc * JCHUNK;
  int r0 = t >> 3;           // row in tile 0..127 (A-gen role)
  int j8 = (t & 7) * 8;      // j offset 0..56
  int iglob = ibase + r0;
  float maxwh2 = fkey_dec(*maxptr);
  float wh1 = Wh1[iglob];
  float m = fmaxf(0.f, wh1 + maxwh2);
  float enm = __expf(-m);
  // A-image: unit = (r0>>4)*2 + (j8>>5); cell swizzled.
  int unitA = (r0 >> 4) * 2 + (j8 >> 5);
  int cA = (r0 & 15) | (((j8 & 31) >> 3) << 4);
  int swA = cA ^ (((cA >> 4) & 3) << 2);
  int aoff = unitA * 1024 + swA * 16;
  int slotR = lane ^ (((lane >> 4) & 3) << 2);
  const int* adjrow = adj + ((size_t)iglob << 13) + jbch + j8;
  // MFMA role: wave (g = wv>>1, h = wv&1) owns f-units {2g,2g+1} and
  // row-blocks {4h..4h+3}. Each A-frag feeds 2 MFMAs (un=0,1).
  int g = wv >> 1, h = wv & 1;
  const char* bbase = WhTf + ((size_t)(kc * 64) << 14) + (size_t)(2 * g) * 1024 +
                      (size_t)lane * 16;
  const char* wl = wlds + j8 * 4;

  // Stage this chunk's Wh2 (2048 floats = 8KB) into LDS once.
  *(float2*)(wlds + t * 8) = *(const float2*)(Wh2 + jbch + t * 2);
  __syncthreads();

  // B regs: [un][ks], double-buffered (bA = even iters, bB = odd).
  bf16x8 bA00, bA01, bA10, bA11, bB00, bB01, bB10, bB11;
  int4 st0_a, st0_b, st1_a, st1_b;
  f32x4 acc[4][2];
#pragma unroll
  for (int a = 0; a < 4; ++a)
#pragma unroll
    for (int b = 0; b < 2; ++b) acc[a][b] = (f32x4){0.f, 0.f, 0.f, 0.f};
  float zacc = 0.f;

#define K3_LDB(S, B00, B01, B10, B11)                                         \
  do {                                                                        \
    int sc_ = (S) < NSTEP ? (S) : NSTEP - 1;                                  \
    const char* bp_ = bbase + (size_t)(2 * sc_) * 16384;                      \
    B00 = *(const bf16x8*)(bp_);                 /* un0 ks0 */                \
    B01 = *(const bf16x8*)(bp_ + 16384);         /* un0 ks1 */                \
    B10 = *(const bf16x8*)(bp_ + 1024);          /* un1 ks0 */                \
    B11 = *(const bf16x8*)(bp_ + 16384 + 1024);  /* un1 ks1 */                \
  } while (0)

#define K3_LDA(S, ST)                                                         \
  do {                                                                        \
    int sc_ = (S) < NSTEP ? (S) : NSTEP - 1;                                  \
    ST##_a = *(const int4*)(adjrow + sc_ * BKJ);                              \
    ST##_b = *(const int4*)(adjrow + sc_ * BKJ + 4);                          \
  } while (0)

#define K3_HV(S, AW, STC)                                                     \
  do {                                                                        \
    float4 wq0_ = *(const float4*)(wl + ((S) + 1) * 256);                     \
    float4 wq1_ = *(const float4*)(wl + ((S) + 1) * 256 + 16);                \
    uint4 a_ = hv8(STC##_a, STC##_b, wq0_, wq1_, wh1, m, enm, zacc);          \
    *(uint4*)((AW) + aoff) = a_;                                              \
  } while (0)

#define K3_MFMA(AR, BC00, BC01, BC10, BC11)                                   \
  do {                                                                        \
    _Pragma("unroll")                                                         \
    for (int rf_ = 0; rf_ < 4; ++rf_) {                                       \
      int ub_ = (h * 4 + rf_) * 2;                                            \
      bf16x8 a0_ = *(const bf16x8*)((AR) + (ub_ + 0) * 1024 + slotR * 16);    \
      bf16x8 a1_ = *(const bf16x8*)((AR) + (ub_ + 1) * 1024 + slotR * 16);    \
      acc[rf_][0] = __builtin_amdgcn_mfma_f32_16x16x32_bf16(a0_, BC00, acc[rf_][0], 0, 0, 0); \
      acc[rf_][1] = __builtin_amdgcn_mfma_f32_16x16x32_bf16(a0_, BC10, acc[rf_][1], 0, 0, 0); \
      acc[rf_][0] = __builtin_amdgcn_mfma_f32_16x16x32_bf16(a1_, BC01, acc[rf_][0], 0, 0, 0); \
      acc[rf_][1] = __builtin_amdgcn_mfma_f32_16x16x32_bf16(a1_, BC11, acc[rf_][1], 0, 0, 0); \
    }                                                                         \
  } while (0)

#define K3_TAIL                                                               \
  do {                                                                        \
    __builtin_amdgcn_sched_barrier(0);                                        \
    asm volatile("s_waitcnt lgkmcnt(0)" ::: "memory");                        \
    __builtin_amdgcn_s_barrier();                                             \
    __builtin_amdgcn_sched_barrier(0);                                        \
  } while (0)

  // Even waves: hv first, then MFMA.  Odd waves: MFMA first, then hv.
#define K3_ITER_H(S, AR, AW, BC00, BC01, BC10, BC11, BF00, BF01, BF10, BF11,  \
                  STC, DO_HV)                                                 \
  do {                                                                        \
    int s_ = (S);                                                             \
    K3_LDB(s_ + 1, BF00, BF01, BF10, BF11);                                   \
    if (DO_HV) K3_HV(s_, AW, STC);                                            \
    K3_LDA(s_ + 3, STC);                                                      \
    K3_MFMA(AR, BC00, BC01, BC10, BC11);                                      \
    K3_TAIL;                                                                  \
  } while (0)

#define K3_ITER_M(S, AR, AW, BC00, BC01, BC10, BC11, BF00, BF01, BF10, BF11,  \
                  STC, DO_HV)                                                 \
  do {                                                                        \
    int s_ = (S);                                                             \
    K3_LDB(s_ + 1, BF00, BF01, BF10, BF11);                                   \
    K3_MFMA(AR, BC00, BC01, BC10, BC11);                                      \
    if (DO_HV) K3_HV(s_, AW, STC);                                            \
    K3_LDA(s_ + 3, STC);                                                      \
    K3_TAIL;                                                                  \
  } while (0)

  // Prologue: B(0)->bA; adj(0) direct; adj(1)->st1, adj(2)->st0; A(0)->abuf0.
  K3_LDB(0, bA00, bA01, bA10, bA11);
  int4 adj0a = *(const int4*)(adjrow);
  int4 adj0b = *(const int4*)(adjrow + 4);
  K3_LDA(1, st1);
  K3_LDA(2, st0);
  {
    float4 wq0 = *(const float4*)(wl);
    float4 wq1 = *(const float4*)(wl + 16);
    uint4 a0 = hv8(adj0a, adj0b, wq0, wq1, wh1, m, enm, zacc);
    *(uint4*)(abuf0 + aoff) = a0;
  }
  K3_TAIL;

  if ((wv & 1) == 0) {
    for (int s2 = 0; s2 < NSTEP - 2; s2 += 2) {
      K3_ITER_H(s2 + 0, abuf0, abuf1, bA00, bA01, bA10, bA11, bB00, bB01,
                bB10, bB11, st1, 1);
      K3_ITER_H(s2 + 1, abuf1, abuf0, bB00, bB01, bB10, bB11, bA00, bA01,
                bA10, bA11, st0, 1);
    }
    K3_ITER_H(NSTEP - 2, abuf0, abuf1, bA00, bA01, bA10, bA11, bB00, bB01,
              bB10, bB11, st1, 1);
    K3_ITER_H(NSTEP - 1, abuf1, abuf0, bB00, bB01, bB10, bB11, bA00, bA01,
              bA10, bA11, st0, 0);
  } else {
    for (int s2 = 0; s2 < NSTEP - 2; s2 += 2) {
      K3_ITER_M(s2 + 0, abuf0, abuf1, bA00, bA01, bA10, bA11, bB00, bB01,
                bB10, bB11, st1, 1);
      K3_ITER_M(s2 + 1, abuf1, abuf0, bB00, bB01, bB10, bB11, bA00, bA01,
                bA10, bA11, st0, 1);
    }
    K3_ITER_M(NSTEP - 2, abuf0, abuf1, bA00, bA01, bA10, bA11, bB00, bB01,
              bB10, bB11, st1, 1);
    K3_ITER_M(NSTEP - 1, abuf1, abuf0, bB00, bB01, bB10, bB11, bA00, bA01,
              bA10, bA11, st0, 0);
  }
#undef K3_ITER_H
#undef K3_ITER_M
#undef K3_TAIL
#undef K3_MFMA
#undef K3_HV
#undef K3_LDA
#undef K3_LDB

  // Z reduce over the 8 threads sharing row r0 (A-gen role).
  zacc += __shfl_xor(zacc, 1);
  zacc += __shfl_xor(zacc, 2);
  zacc += __shfl_xor(zacc, 4);
  if ((t & 7) == 0) Zp[(size_t)kc * NR + iglob] = zacc;
#pragma unroll
  for (int rf = 0; rf < 4; ++rf)
#pragma unroll
    for (int un = 0; un < 2; ++un) {
      int f = (2 * g + un) * 16 + (lane & 15);
      int row0 = ibase + (h * 4 + rf) * 16 + ((lane >> 4) << 2);
      size_t base = ((size_t)kc * NR + row0) * FOUT + f;
      PVp[base + 0 * FOUT] = acc[rf][un].x;
      PVp[base + 1 * FOUT] = acc[rf][un].y;
      PVp[base + 2 * FOUT] = acc[rf][un].z;
      PVp[base + 3 * FOUT] = acc[rf][un].w;
    }
}

// ---------------- k4: reduce partials, normalize, relu ----------------
__global__ __launch_bounds__(256) void k4_reduce(const float* __restrict__ PVp,
                                                 const float* __restrict__ Zp,
                                                 float* __restrict__ out) {
  int tid = blockIdx.x * 256 + threadIdx.x;  // 0..524287
  int i = tid >> 6;
  int f4 = (tid & 63) * 4;
  float z = Zp[i] + Zp[NR + i] + Zp[2 * NR + i] + Zp[3 * NR + i];
  float4 a = {0.f, 0.f, 0.f, 0.f};
#pragma unroll
  for (int c = 0; c < KSPLIT; ++c) {
    float4 p = *(const float4*)(PVp + ((size_t)c * NR + i) * FOUT + f4);
    a.x += p.x;
    a.y += p.y;
    a.z += p.z;
    a.w += p.w;
  }
  float inv = 1.f / z;
  float4 r;
  r.x = fmaxf(a.x * inv, 0.f);
  r.y = fmaxf(a.y * inv, 0.f);
  r.z = fmaxf(a.z * inv, 0.f);
  r.w = fmaxf(a.w * inv, 0.f);
  *(float4*)(out + (size_t)i * FOUT + f4) = r;
}

// ---------------- launch ----------------
extern "C" void kernel_launch(void* const* d_in, const int* in_sizes, int n_in,
                              void* d_out, int out_size, void* d_ws,
                              size_t ws_size, hipStream_t stream) {
  const float* X = (const float*)d_in[0];
  const float* W = (const float*)d_in[1];
  const float* W2 = (const float*)d_in[2];
  const int* adj = (const int*)d_in[3];
  float* out = (float*)d_out;
  char* ws = (char*)d_ws;

  const size_t WHT_OFF = 0;                               // 4 MB fragment image
  const size_t WTBF_OFF = (size_t)4 * 1024 * 1024;        // 256 KB
  const size_t W1_OFF = WTBF_OFF + 256 * 1024;
  const size_t W2V_OFF = W1_OFF + 2048;
  const size_t WH1_OFF = W2V_OFF + 2048;
  const size_t WH2_OFF = WH1_OFF + 32768;
  const size_t MXK_OFF = WH2_OFF + 32768;
  const size_t ZP_OFF = MXK_OFF + 256;                    // float[4][8192]
  const size_t PV_OFF = ZP_OFF + (size_t)KSPLIT * NR * 4; // float[4][8192][256]

  char* WhTf = ws + WHT_OFF;
  char* WTbf = ws + WTBF_OFF;
  float* w1 = (float*)(ws + W1_OFF);
  float* w2 = (float*)(ws + W2V_OFF);
  float* Wh1 = (float*)(ws + WH1_OFF);
  float* Wh2 = (float*)(ws + WH2_OFF);
  unsigned* maxkey = (unsigned*)(ws + MXK_OFF);
  float* Zp = (float*)(ws + ZP_OFF);
  float* PVp = (float*)(ws + PV_OFF);

  k0_prep<<<128, 256, 0, stream>>>(W, W2, w1, w2, WTbf, maxkey);
  k2_fused<<<256, 256, 0, stream>>>(X, WTbf, w1, w2, WhTf, Wh1, Wh2, maxkey);
  k3_attn<<<256, 1024, 0, stream>>>(adj, WhTf, Wh1, Wh2, maxkey, PVp, Zp);
  k4_reduce<<<2048, 256, 0, stream>>>(PVp, Zp, out);
}